// Round 4
// baseline (204.872 us; speedup 1.0000x reference)
//
#include <hip/hip_runtime.h>

// VQ: z [32,256,32,32] f32, codebook [1024,256] f32
// out: z_q [32,256,32,32] f32 (8388608) then loss scalar f32 (1)
#define NELEM 8388608

typedef __attribute__((ext_vector_type(4))) float f32x4;
typedef unsigned long long ull;

// ---------------------------------------------------------------------------
// prep: codebook -> fp8 e4m3 (scaled x256, exact pow2) in B-fragment-linear
// order for mfma_f32_16x16x32_fp8_fp8, plus exact fp32 norms cn[k].
// frag g = nt*8+ks (512 B): lane L holds cb[nt*16+(L&15)][ks*32+(L>>4)*8+0..7]
// Also zeroes the loss scalar (replaces a separate hipMemsetAsync dispatch).
__global__ __launch_bounds__(256) void prep_kernel(const float* __restrict__ cb,
                                                   uint2* __restrict__ cbf8,
                                                   float* __restrict__ cn,
                                                   float* __restrict__ loss) {
    if (blockIdx.x == 0 && threadIdx.x == 0) *loss = 0.f;

    const int t = threadIdx.x;
    const int gt = blockIdx.x * 256 + t;          // 0..32767
    const int L = gt & 63, g = gt >> 6;           // frag 0..511
    const int nt = g >> 3, ks = g & 7;
    const int code = nt * 16 + (L & 15);
    const int k0 = ks * 32 + (L >> 4) * 8;
    const float* s = cb + code * 256 + k0;
    float v[8];
    #pragma unroll
    for (int j = 0; j < 8; ++j) v[j] = s[j] * 256.0f;
    int lo = 0, hi = 0;
    lo = __builtin_amdgcn_cvt_pk_fp8_f32(v[0], v[1], lo, false);
    lo = __builtin_amdgcn_cvt_pk_fp8_f32(v[2], v[3], lo, true);
    hi = __builtin_amdgcn_cvt_pk_fp8_f32(v[4], v[5], hi, false);
    hi = __builtin_amdgcn_cvt_pk_fp8_f32(v[6], v[7], hi, true);
    uint2 o; o.x = (unsigned)lo; o.y = (unsigned)hi;
    cbf8[g * 64 + L] = o;

    const int w = t >> 6, lane = t & 63;
    #pragma unroll
    for (int cc = 0; cc < 2; ++cc) {
        int cd = blockIdx.x * 8 + w * 2 + cc;
        float4 qv = *(const float4*)(cb + cd * 256 + lane * 4);
        float s2 = qv.x*qv.x + qv.y*qv.y + qv.z*qv.z + qv.w*qv.w;
        #pragma unroll
        for (int off = 32; off; off >>= 1) s2 += __shfl_down(s2, off, 64);
        if (lane == 0) cn[cd] = s2;
    }
}

// ---------------------------------------------------------------------------
// Fused argmin + gather + transpose-store + loss.
// Grid 1024 blocks x 256 thr. Block = 32 pos x 1024 codes. LDS ~34 KB ->
// 4 blocks/CU; loop state ~90 VGPR (natural alloc, NO forced waves cap —
// r2's (256,4) and r3's DMA structure both spilled ~100+ MB of scratch).
// B chunk (64 codes, 16 KB) single-buffered with r1's PROVEN VGPR-staged
// prefetch, issued 2 iters ahead: ds_read breg -> barrier -> ds_write
// chunk it+1 (regs) -> issue loads chunk it+2 -> MFMA/min -> barrier.
// Per iter wave w owns nt-group it*4+w against both m-frags (16 MFMAs, 4
// indep chains). A-frags exchanged once via LDS -> 32 VGPRs. dist =
// cn - 2*dot; nt packed in 6 low mantissa bits.
// loss = 1.25/NELEM * sum(z^2_exact + dmin).
__global__ __launch_bounds__(256, 2) void vq_kernel(
        const float* __restrict__ z, const uint4* __restrict__ cbf8,
        const float* __restrict__ cb, const float* __restrict__ cn,
        float* __restrict__ out, float* __restrict__ loss) {
    __shared__ union {
        struct {
            float cn[1024];          // 4 KB
            uint4 B[1024];           // 16 KB single-buffered fp8 chunk
            ull   A[2][8][64];       // 8 KB one-time A-frag exchange
        } p1;                        // 28 KB
        float Q[32][257];            // 32.9 KB (epilogue transpose)
    } S;
    __shared__ int   codeS[32];
    __shared__ float Dw[4][32];
    __shared__ int   Cw[4][32];
    __shared__ float wsum[4];

    const int t = threadIdx.x, w = t >> 6, L = t & 63;
    const int col = L & 15, q = L >> 4;
    const int blk = blockIdx.x;                 // 0..1023
    const int b = blk >> 5, hw0 = (blk & 31) << 5;

    // chunk 0 loads (issued first; arrive during the long A phase)
    uint4 st0[4];
    #pragma unroll
    for (int i = 0; i < 4; ++i) st0[i] = cbf8[(i << 8) + t];

    // stage cn
    *(float4*)&S.p1.cn[t * 4] = *(const float4*)(cn + t * 4);

    // A phase: wave w -> m-frag mi = w&1 (pos mi*16..+15), ks in [ksb,ksb+4)
    // (32 floats/lane). z scaled x16 -> fp8; exact fp32 z^2 from same loads.
    const int mi = w & 1, ksb = (w >> 1) * 4;
    ull af[4];
    float z2 = 0.f;
    const float* zb = z + ((size_t)b << 18) + hw0;
    {
        const float* zp = zb + (mi * 16 + col) + (((ksb * 32) + q * 8) << 10);
        #pragma unroll
        for (int kk = 0; kk < 4; ++kk) {
            const float* sp = zp + ((kk * 32) << 10);
            float v[8];
            #pragma unroll
            for (int j = 0; j < 8; ++j) v[j] = sp[j << 10];
            #pragma unroll
            for (int j = 0; j < 8; ++j) z2 += v[j] * v[j];
            int lo = 0, hi = 0;
            lo = __builtin_amdgcn_cvt_pk_fp8_f32(v[0]*16.f, v[1]*16.f, lo, false);
            lo = __builtin_amdgcn_cvt_pk_fp8_f32(v[2]*16.f, v[3]*16.f, lo, true);
            hi = __builtin_amdgcn_cvt_pk_fp8_f32(v[4]*16.f, v[5]*16.f, hi, false);
            hi = __builtin_amdgcn_cvt_pk_fp8_f32(v[6]*16.f, v[7]*16.f, hi, true);
            af[kk] = ((ull)(unsigned)hi << 32) | (unsigned)lo;
        }
    }

    // share A-frags; stage chunk 0; issue chunk 1 loads
    #pragma unroll
    for (int kk = 0; kk < 4; ++kk) S.p1.A[mi][ksb + kk][L] = af[kk];
    #pragma unroll
    for (int i = 0; i < 4; ++i) S.p1.B[(i << 8) + t] = st0[i];

    uint4 st[4];
    #pragma unroll
    for (int i = 0; i < 4; ++i) st[i] = cbf8[(1 << 10) + (i << 8) + t];

    __syncthreads();   // chunk 0 / A / cn visible

    // both m-frags into registers (one-time, 2-way bank aliasing = free)
    ull am[2][8];
    #pragma unroll
    for (int m2 = 0; m2 < 2; ++m2)
        #pragma unroll
        for (int ks = 0; ks < 8; ++ks)
            am[m2][ks] = S.p1.A[m2][ks][L];

    float minv[2][4];
    #pragma unroll
    for (int m2 = 0; m2 < 2; ++m2)
        #pragma unroll
        for (int r = 0; r < 4; ++r) minv[m2][r] = 3.4e38f;

    const float SC = -4.8828125e-4f;   // -2 / (16*256)
    for (int it = 0; it < 16; ++it) {
        // wave w reads its nt-group's 8 frags (4 KB) from the chunk
        const ull* bb = (const ull*)&S.p1.B[0];
        ull breg[8];
        #pragma unroll
        for (int ks = 0; ks < 8; ++ks)
            breg[ks] = bb[((w * 8 + ks) << 6) + L];

        const int nt = it * 4 + w;
        const float cnv = S.p1.cn[(nt << 4) + col];

        __syncthreads();                  // all waves' B reads complete

        if (it < 15) {                    // stage chunk it+1 (arrived long ago)
            #pragma unroll
            for (int i = 0; i < 4; ++i) S.p1.B[(i << 8) + t] = st[i];
        }
        if (it < 14) {                    // issue chunk it+2: a full iter of cover
            #pragma unroll
            for (int i = 0; i < 4; ++i) st[i] = cbf8[((it + 2) << 10) + (i << 8) + t];
        }

        // 4 independent MFMA chains of depth 4 (split-ks accumulators)
        f32x4 a0 = {0,0,0,0}, a0b = {0,0,0,0}, a1 = {0,0,0,0}, a1b = {0,0,0,0};
        #pragma unroll
        for (int kk = 0; kk < 4; ++kk) {
            a0  = __builtin_amdgcn_mfma_f32_16x16x32_fp8_fp8((long long)am[0][2*kk],   (long long)breg[2*kk],   a0,  0, 0, 0);
            a0b = __builtin_amdgcn_mfma_f32_16x16x32_fp8_fp8((long long)am[0][2*kk+1], (long long)breg[2*kk+1], a0b, 0, 0, 0);
            a1  = __builtin_amdgcn_mfma_f32_16x16x32_fp8_fp8((long long)am[1][2*kk],   (long long)breg[2*kk],   a1,  0, 0, 0);
            a1b = __builtin_amdgcn_mfma_f32_16x16x32_fp8_fp8((long long)am[1][2*kk+1], (long long)breg[2*kk+1], a1b, 0, 0, 0);
        }
        a0 = a0 + a0b;
        a1 = a1 + a1b;

        const unsigned pn = (unsigned)nt;                  // 6 bits
        #pragma unroll
        for (int m2 = 0; m2 < 2; ++m2) {
            const f32x4& aa = m2 ? a1 : a0;
            #pragma unroll
            for (int r = 0; r < 4; ++r) {
                float d = fmaf(SC, aa[r], cnv);
                d = __uint_as_float((__float_as_uint(d) & ~63u) | pn);
                minv[m2][r] = fminf(minv[m2][r], d);
            }
        }
        if (it < 15) __syncthreads();     // chunk it+1 visible
    }

    // within-wave min over the 16 code-cols; winners -> LDS (packed v kept)
    #pragma unroll
    for (int m2 = 0; m2 < 2; ++m2) {
        #pragma unroll
        for (int r = 0; r < 4; ++r) {
            float v = minv[m2][r];
            int cd = ((__float_as_int(v) & 63) << 4) | col;
            #pragma unroll
            for (int d = 1; d < 16; d <<= 1) {
                float ov = __shfl_xor(v, d, 64);
                int   oc = __shfl_xor(cd, d, 64);
                if (ov < v || (ov == v && oc < cd)) { v = ov; cd = oc; }
            }
            if (col == 0) {
                int p = m2 * 16 + q * 4 + r;   // position 0..31
                Dw[w][p] = v;
                Cw[w][p] = cd;
            }
        }
    }
    __syncthreads();

    // cross-wave min (each wave held a disjoint quarter of the codes)
    float dpart = 0.f;
    if (w == 0 && L < 32) {
        float v = Dw[0][L]; int cd = Cw[0][L];
        #pragma unroll
        for (int ww = 1; ww < 4; ++ww) {
            float ov = Dw[ww][L]; int oc = Cw[ww][L];
            if (ov < v || (ov == v && oc < cd)) { v = ov; cd = oc; }
        }
        codeS[L] = cd;
        dpart = __uint_as_float(__float_as_uint(v) & ~63u);
    }

    float tot = z2 + dpart;
    #pragma unroll
    for (int off = 32; off; off >>= 1) tot += __shfl_down(tot, off, 64);
    if (L == 0) wsum[w] = tot;
    __syncthreads();
    if (t == 0)
        atomicAdd(loss, (wsum[0] + wsum[1] + wsum[2] + wsum[3]) * (1.25f / (float)NELEM));

    // Phase C/D: gather fp32 codebook rows (coalesced), transpose via LDS,
    // write out. Single 32-pos pass through Q[32][257] -> 128 B contiguous
    // output segments (8 lanes x 16 B per channel row).
    const size_t obase = ((size_t)b << 18) + hw0;
    const int pg = L & 7, cidx = L >> 3;
    __syncthreads();                       // loop LDS dead; Q may alias
    #pragma unroll
    for (int rr = 0; rr < 8; ++rr) {
        int row = w * 8 + rr;              // 0..31
        int code = codeS[row];
        float4 v = *(const float4*)(cb + ((size_t)code << 8) + (L << 2));
        float* qp = &S.Q[row][L << 2];
        qp[0] = v.x; qp[1] = v.y; qp[2] = v.z; qp[3] = v.w;
    }
    __syncthreads();
    #pragma unroll
    for (int i = 0; i < 8; ++i) {
        int c = w * 64 + i * 8 + cidx;
        int p0 = pg * 4;
        float4 qv;
        qv.x = S.Q[p0 + 0][c]; qv.y = S.Q[p0 + 1][c];
        qv.z = S.Q[p0 + 2][c]; qv.w = S.Q[p0 + 3][c];
        *(float4*)(out + obase + ((size_t)c << 10) + p0) = qv;
    }
}

// ---------------------------------------------------------------------------
extern "C" void kernel_launch(void* const* d_in, const int* in_sizes, int n_in,
                              void* d_out, int out_size, void* d_ws, size_t ws_size,
                              hipStream_t stream) {
    const float* z  = (const float*)d_in[0];
    const float* cb = (const float*)d_in[1];
    float* out  = (float*)d_out;
    float* cn   = (float*)d_ws;                              // 4 KB
    uint2* cbf8 = (uint2*)((char*)d_ws + 4096);              // 256 KB
    float* loss = out + NELEM;

    prep_kernel<<<128, 256, 0, stream>>>(cb, cbf8, cn, loss);
    vq_kernel<<<1024, 256, 0, stream>>>(z, (const uint4*)cbf8, cb, cn, out, loss);
}

// Round 5
// 116.838 us; speedup vs baseline: 1.7535x; 1.7535x over previous
//
#include <hip/hip_runtime.h>

// VQ: z [32,256,32,32] f32, codebook [1024,256] f32
// out: z_q [32,256,32,32] f32 (8388608) then loss scalar f32 (1)
#define NELEM 8388608

typedef __attribute__((ext_vector_type(4))) float f32x4;
typedef unsigned long long ull;

// ---------------------------------------------------------------------------
// prep: codebook -> fp8 e4m3 (scaled x256, exact pow2) in B-fragment-linear
// order for mfma_f32_16x16x32_fp8_fp8, plus exact fp32 norms cn[k].
// frag g = nt*8+ks (512 B): lane L holds cb[nt*16+(L&15)][ks*32+(L>>4)*8+0..7]
// Also zeroes the loss scalar (replaces a separate hipMemsetAsync dispatch).
__global__ __launch_bounds__(256) void prep_kernel(const float* __restrict__ cb,
                                                   uint2* __restrict__ cbf8,
                                                   float* __restrict__ cn,
                                                   float* __restrict__ loss) {
    if (blockIdx.x == 0 && threadIdx.x == 0) *loss = 0.f;

    const int t = threadIdx.x;
    const int gt = blockIdx.x * 256 + t;          // 0..32767
    const int L = gt & 63, g = gt >> 6;           // frag 0..511
    const int nt = g >> 3, ks = g & 7;
    const int code = nt * 16 + (L & 15);
    const int k0 = ks * 32 + (L >> 4) * 8;
    const float* s = cb + code * 256 + k0;
    float v[8];
    #pragma unroll
    for (int j = 0; j < 8; ++j) v[j] = s[j] * 256.0f;
    int lo = 0, hi = 0;
    lo = __builtin_amdgcn_cvt_pk_fp8_f32(v[0], v[1], lo, false);
    lo = __builtin_amdgcn_cvt_pk_fp8_f32(v[2], v[3], lo, true);
    hi = __builtin_amdgcn_cvt_pk_fp8_f32(v[4], v[5], hi, false);
    hi = __builtin_amdgcn_cvt_pk_fp8_f32(v[6], v[7], hi, true);
    uint2 o; o.x = (unsigned)lo; o.y = (unsigned)hi;
    cbf8[g * 64 + L] = o;

    const int w = t >> 6, lane = t & 63;
    #pragma unroll
    for (int cc = 0; cc < 2; ++cc) {
        int cd = blockIdx.x * 8 + w * 2 + cc;
        float4 qv = *(const float4*)(cb + cd * 256 + lane * 4);
        float s2 = qv.x*qv.x + qv.y*qv.y + qv.z*qv.z + qv.w*qv.w;
        #pragma unroll
        for (int off = 32; off; off >>= 1) s2 += __shfl_down(s2, off, 64);
        if (lane == 0) cn[cd] = s2;
    }
}

// ---------------------------------------------------------------------------
// Fused argmin + gather + transpose-store + loss.
// Grid 1024 blocks x 256 thr. Block = 32 pos x 1024 codes.
//
// KEY CHANGE (r5): NO LDS staging of B at all. cbf8 (256 KB) is L2-resident
// on every XCD; each wave loads its fragments straight from L2 (512 B
// coalesced per frag). The main loop is BARRIER-FREE: waves drift, TLP
// (4 blocks/CU x 4 waves) hides the ~200 cyc L2 latency. This removes the
// prefetch register state that made r2/r3/r4 spill (r4: 128 VGPR +
// 130 MB scratch writes) and all 32 per-iter barrier drains.
//
// Wave w owns nt-groups w*16..w*16+15 (16 codes x 16 iters) against both
// m-frags (16 MFMAs/iter, 4 indep chains). A-frags exchanged once via LDS
// -> 32 VGPRs. dist = cn - 2*dot; nt packed in 6 low mantissa bits;
// cross-wave argmin combine at the end. LDS ~33.5 KB -> 4 blocks/CU.
// loss = 1.25/NELEM * sum(z^2_exact + dmin).
__global__ __launch_bounds__(256) void vq_kernel(
        const float* __restrict__ z, const uint4* __restrict__ cbf8,
        const float* __restrict__ cb, const float* __restrict__ cn,
        float* __restrict__ out, float* __restrict__ loss) {
    __shared__ union {
        struct {
            float cn[1024];          // 4 KB
            ull   A[2][8][64];       // 8 KB one-time A-frag exchange
        } p1;                        // 12 KB
        float Q[32][257];            // 32.9 KB (epilogue transpose)
    } S;
    __shared__ int   codeS[32];
    __shared__ float Dw[4][32];
    __shared__ int   Cw[4][32];
    __shared__ float wsum[4];

    const int t = threadIdx.x, w = t >> 6, L = t & 63;
    const int col = L & 15, q = L >> 4;
    const int blk = blockIdx.x;                 // 0..1023
    const int b = blk >> 5, hw0 = (blk & 31) << 5;

    // stage cn
    *(float4*)&S.p1.cn[t * 4] = *(const float4*)(cn + t * 4);

    // A phase: wave w -> m-frag mi = w&1 (pos mi*16..+15), ks in [ksb,ksb+4)
    // (32 floats/lane). z scaled x16 -> fp8; exact fp32 z^2 from same loads.
    const int mi = w & 1, ksb = (w >> 1) * 4;
    ull af[4];
    float z2 = 0.f;
    const float* zb = z + ((size_t)b << 18) + hw0;
    {
        const float* zp = zb + (mi * 16 + col) + (((ksb * 32) + q * 8) << 10);
        #pragma unroll
        for (int kk = 0; kk < 4; ++kk) {
            const float* sp = zp + ((kk * 32) << 10);
            float v[8];
            #pragma unroll
            for (int j = 0; j < 8; ++j) v[j] = sp[j << 10];
            #pragma unroll
            for (int j = 0; j < 8; ++j) z2 += v[j] * v[j];
            int lo = 0, hi = 0;
            lo = __builtin_amdgcn_cvt_pk_fp8_f32(v[0]*16.f, v[1]*16.f, lo, false);
            lo = __builtin_amdgcn_cvt_pk_fp8_f32(v[2]*16.f, v[3]*16.f, lo, true);
            hi = __builtin_amdgcn_cvt_pk_fp8_f32(v[4]*16.f, v[5]*16.f, hi, false);
            hi = __builtin_amdgcn_cvt_pk_fp8_f32(v[6]*16.f, v[7]*16.f, hi, true);
            af[kk] = ((ull)(unsigned)hi << 32) | (unsigned)lo;
        }
    }

    // share A-frags (wave w's af[kk] at lane L IS (mi, ksb+kk) for everyone)
    #pragma unroll
    for (int kk = 0; kk < 4; ++kk) S.p1.A[mi][ksb + kk][L] = af[kk];

    __syncthreads();   // A / cn visible; ONLY barrier before the epilogue

    // both m-frags into registers (one-time, 2-way bank aliasing = free)
    ull am[2][8];
    #pragma unroll
    for (int m2 = 0; m2 < 2; ++m2)
        #pragma unroll
        for (int ks = 0; ks < 8; ++ks)
            am[m2][ks] = S.p1.A[m2][ks][L];

    float minv[2][4];
    #pragma unroll
    for (int m2 = 0; m2 < 2; ++m2)
        #pragma unroll
        for (int r = 0; r < 4; ++r) minv[m2][r] = 3.4e38f;

    const float SC = -4.8828125e-4f;   // -2 / (16*256)
    const ull* __restrict__ bg = (const ull*)cbf8;

    #pragma unroll 1
    for (int it = 0; it < 16; ++it) {
        const int nt = (w << 4) + it;          // wave-contiguous 64 KB slab
        // B frags straight from L2: 8 x global_load_dwordx2, 512 B/frag
        ull breg[8];
        #pragma unroll
        for (int ks = 0; ks < 8; ++ks)
            breg[ks] = bg[((nt * 8 + ks) << 6) + L];
        const float cnv = S.p1.cn[(nt << 4) + col];

        // 4 independent MFMA chains of depth 4 (split-ks accumulators)
        f32x4 a0 = {0,0,0,0}, a0b = {0,0,0,0}, a1 = {0,0,0,0}, a1b = {0,0,0,0};
        #pragma unroll
        for (int kk = 0; kk < 4; ++kk) {
            a0  = __builtin_amdgcn_mfma_f32_16x16x32_fp8_fp8((long long)am[0][2*kk],   (long long)breg[2*kk],   a0,  0, 0, 0);
            a0b = __builtin_amdgcn_mfma_f32_16x16x32_fp8_fp8((long long)am[0][2*kk+1], (long long)breg[2*kk+1], a0b, 0, 0, 0);
            a1  = __builtin_amdgcn_mfma_f32_16x16x32_fp8_fp8((long long)am[1][2*kk],   (long long)breg[2*kk],   a1,  0, 0, 0);
            a1b = __builtin_amdgcn_mfma_f32_16x16x32_fp8_fp8((long long)am[1][2*kk+1], (long long)breg[2*kk+1], a1b, 0, 0, 0);
        }
        a0 = a0 + a0b;
        a1 = a1 + a1b;

        const unsigned pn = (unsigned)nt;                  // 6 bits
        #pragma unroll
        for (int m2 = 0; m2 < 2; ++m2) {
            const f32x4& aa = m2 ? a1 : a0;
            #pragma unroll
            for (int r = 0; r < 4; ++r) {
                float d = fmaf(SC, aa[r], cnv);
                d = __uint_as_float((__float_as_uint(d) & ~63u) | pn);
                minv[m2][r] = fminf(minv[m2][r], d);
            }
        }
    }

    // within-wave min over the 16 code-cols; winners -> LDS (packed v kept)
    #pragma unroll
    for (int m2 = 0; m2 < 2; ++m2) {
        #pragma unroll
        for (int r = 0; r < 4; ++r) {
            float v = minv[m2][r];
            int cd = ((__float_as_int(v) & 63) << 4) | col;
            #pragma unroll
            for (int d = 1; d < 16; d <<= 1) {
                float ov = __shfl_xor(v, d, 64);
                int   oc = __shfl_xor(cd, d, 64);
                if (ov < v || (ov == v && oc < cd)) { v = ov; cd = oc; }
            }
            if (col == 0) {
                int p = m2 * 16 + q * 4 + r;   // position 0..31
                Dw[w][p] = v;
                Cw[w][p] = cd;
            }
        }
    }
    __syncthreads();   // all waves done with loop (cn dead) + Dw/Cw visible

    // cross-wave min (each wave held a disjoint quarter of the codes)
    float dpart = 0.f;
    if (w == 0 && L < 32) {
        float v = Dw[0][L]; int cd = Cw[0][L];
        #pragma unroll
        for (int ww = 1; ww < 4; ++ww) {
            float ov = Dw[ww][L]; int oc = Cw[ww][L];
            if (ov < v || (ov == v && oc < cd)) { v = ov; cd = oc; }
        }
        codeS[L] = cd;
        dpart = __uint_as_float(__float_as_uint(v) & ~63u);
    }

    float tot = z2 + dpart;
    #pragma unroll
    for (int off = 32; off; off >>= 1) tot += __shfl_down(tot, off, 64);
    if (L == 0) wsum[w] = tot;
    __syncthreads();
    if (t == 0)
        atomicAdd(loss, (wsum[0] + wsum[1] + wsum[2] + wsum[3]) * (1.25f / (float)NELEM));

    // Phase C/D: gather fp32 codebook rows (coalesced), transpose via LDS,
    // write out. Single 32-pos pass through Q[32][257] -> 128 B contiguous
    // output segments (8 lanes x 16 B per channel row).
    const size_t obase = ((size_t)b << 18) + hw0;
    const int pg = L & 7, cidx = L >> 3;
    __syncthreads();                       // loop LDS dead; Q may alias
    #pragma unroll
    for (int rr = 0; rr < 8; ++rr) {
        int row = w * 8 + rr;              // 0..31
        int code = codeS[row];
        float4 v = *(const float4*)(cb + ((size_t)code << 8) + (L << 2));
        float* qp = &S.Q[row][L << 2];
        qp[0] = v.x; qp[1] = v.y; qp[2] = v.z; qp[3] = v.w;
    }
    __syncthreads();
    #pragma unroll
    for (int i = 0; i < 8; ++i) {
        int c = w * 64 + i * 8 + cidx;
        int p0 = pg * 4;
        float4 qv;
        qv.x = S.Q[p0 + 0][c]; qv.y = S.Q[p0 + 1][c];
        qv.z = S.Q[p0 + 2][c]; qv.w = S.Q[p0 + 3][c];
        *(float4*)(out + obase + ((size_t)c << 10) + p0) = qv;
    }
}

// ---------------------------------------------------------------------------
extern "C" void kernel_launch(void* const* d_in, const int* in_sizes, int n_in,
                              void* d_out, int out_size, void* d_ws, size_t ws_size,
                              hipStream_t stream) {
    const float* z  = (const float*)d_in[0];
    const float* cb = (const float*)d_in[1];
    float* out  = (float*)d_out;
    float* cn   = (float*)d_ws;                              // 4 KB
    uint2* cbf8 = (uint2*)((char*)d_ws + 4096);              // 256 KB
    float* loss = out + NELEM;

    prep_kernel<<<128, 256, 0, stream>>>(cb, cbf8, cn, loss);
    vq_kernel<<<1024, 256, 0, stream>>>(z, (const uint4*)cbf8, cb, cn, out, loss);
}